// Round 14
// baseline (33.204 us; speedup 1.0000x reference)
//
#include <hip/hip_runtime.h>
#include <math.h>

// Banded unbalanced Sinkhorn OT -> disparity. One (b,h) problem per block,
// 6 waves, ONE block barrier per Sinkhorn iteration. Wave w owns rows
// j in [52w,52w+52) and redundantly computes the 99 G values those rows need
// (wave-private LDS strips, intra-wave ordering via lgkmcnt+sched_barrier).
// ALL weights (2 col windows + 1 row window, fp16-pair packed) live in
// registers. E = 2^f double-buffered fp16 with even/odd parity replicas.
// Uniform shifts ride in an end-of-kernel scalar recurrence over 21 stored
// reduction values (per-lane y[21] in registers, reduced once via DPP).

typedef _Float16 half1;
typedef _Float16 half2v __attribute__((ext_vector_type(2)));

#define MAXD   48
#define WROWS  312
#define CCOLS  360
#define NITER  10
#define NT     384
#define NWAVE  6
#define NACC   21
#define GSS    52

__device__ __forceinline__ half2v h2(unsigned v) { return __builtin_bit_cast(half2v, v); }
__device__ __forceinline__ unsigned packf(float x, float y) {
    half2v v; v[0] = (half1)x; v[1] = (half1)y;
    return __builtin_bit_cast(unsigned, v);
}
__device__ __forceinline__ float fdot2(unsigned a, unsigned b, float c) {
    return __builtin_amdgcn_fdot2(h2(a), h2(b), c, false);
}
__device__ __forceinline__ float fdot2h(half2v a, unsigned b, float c) {
    return __builtin_amdgcn_fdot2(a, h2(b), c, false);
}
template <int CTRL>
__device__ __forceinline__ float dpp_add(float x, float acc) {
    int y = __builtin_amdgcn_update_dpp(0, __float_as_int(x), CTRL, 0xf, 0xf, true);
    return acc + __int_as_float(y);
}
__device__ __forceinline__ float dpp_sum64(float x) {   // valid in lane 63
    x = dpp_add<0x111>(x, x);
    x = dpp_add<0x112>(x, x);
    x = dpp_add<0x114>(x, x);
    x = dpp_add<0x118>(x, x);
    x = dpp_add<0x142>(x, x);
    x = dpp_add<0x143>(x, x);
    return x;
}

__global__ __launch_bounds__(NT, 1)
void ot_disp_kernel(const float* __restrict__ scores, float* __restrict__ out) {
    const int tid = threadIdx.x;
    const int wid = tid >> 6;
    const int L   = tid & 63;
    const int bid = blockIdx.x;                 // 0..127 (= b*64 + h)
    const int b   = bid >> 6, h = bid & 63;

    const float LOG_A2 = -8.2854022f;   // -log2(312)
    const float LOG_B2 = -8.4918531f;   // -log2(360)
    const float TAU = 0.95f, KAPPA = 0.025f, XI = 0.025641026f;
    const float RHO = 19.0f, INVRHO = 0.052631579f, TIR = 0.05f;

    // Ebuf[buf][parity][204] dwords: parity0 holds E[p] at half p,
    // parity1 holds E[p] at half p+1 (p = j+48 in [48,360)).
    __shared__ unsigned Ebuf[2][2][204];
    __shared__ unsigned GS_A[NWAVE * GSS], GS_B[NWAVE * GSS];
    __shared__ float s_red[NACC * NWAVE];

    // ---- guard zeros, DISJOINT from written halves (no race with init) ----
    if (tid < 48) {
        int dw = (tid < 24) ? tid : (180 + tid - 24);
        Ebuf[0][0][dw] = 0u; Ebuf[1][0][dw] = 0u;
    } else if (tid < 95) {
        int q = tid - 48;
        int dw = (q < 24) ? q : (181 + q - 24);      // q 24..46 -> 181..203
        Ebuf[0][1][dw] = 0u; Ebuf[1][1][dw] = 0u;
    } else if (tid == 95) {
        ((half1*)Ebuf[0][1])[48]  = (half1)0.f; ((half1*)Ebuf[1][1])[48]  = (half1)0.f;
        ((half1*)Ebuf[0][1])[361] = (half1)0.f; ((half1*)Ebuf[1][1])[361] = (half1)0.f;
    }

    const float* src = scores + ((size_t)(b * MAXD) * 64 + h) * WROWS;
    const size_t dstr = (size_t)64 * WROWS;

    const bool rowAct = (L < 52);
    const int  j   = 52 * wid + (rowAct ? L : 51);
    const int  c0  = 52 * wid + 1 + L;          // first owned column (<=324)
    const bool v1  = (L < 35);                  // second column c1 = c0+64 (<360)

    // ---- register weight caches (72 dwords), straight from global ----
    unsigned wc0[24], wc1[24], wrow[24];
    #pragma unroll
    for (int t = 0; t < 24; ++t) {
        int ja = c0 - MAXD + 2 * t;
        bool va = (unsigned)ja < (unsigned)WROWS;
        bool vb = (unsigned)(ja + 1) < (unsigned)WROWS;
        float x0 = va ? __expf(src[(size_t)(2 * t) * dstr + (va ? ja : 0)]) : 0.f;
        float x1 = vb ? __expf(src[(size_t)(2 * t + 1) * dstr + (vb ? ja + 1 : 0)]) : 0.f;
        wc0[t] = packf(x0, x1);
        int jc = ja + 64;
        bool vc = v1 && ((unsigned)jc < (unsigned)WROWS);
        bool vd = v1 && ((unsigned)(jc + 1) < (unsigned)WROWS);
        float x2 = vc ? __expf(src[(size_t)(2 * t) * dstr + (vc ? jc : 0)]) : 0.f;
        float x3 = vd ? __expf(src[(size_t)(2 * t + 1) * dstr + (vd ? jc + 1 : 0)]) : 0.f;
        wc1[t] = packf(x2, x3);
    }
    {
        const float rm = rowAct ? 1.f : 0.f;
        #pragma unroll
        for (int t = 0; t < 24; ++t) {
            float x0 = rm * __expf(src[(size_t)(47 - 2 * t) * dstr + j]);
            float x1 = rm * __expf(src[(size_t)(46 - 2 * t) * dstr + j]);
            wrow[t] = packf(x0, x1);
        }
    }

    // ---- init: Ehat0 = 1/sum(w_row); y[0] partial ----
    const unsigned ONE2 = 0x3C003C00u;
    float y[NACC];
    {
        float s0=0,s1=0,s2=0,s3=0;
        #pragma unroll
        for (int t = 0; t < 24; t += 4) {
            s0 = fdot2(wrow[t],   ONE2, s0);
            s1 = fdot2(wrow[t+1], ONE2, s1);
            s2 = fdot2(wrow[t+2], ONE2, s2);
            s3 = fdot2(wrow[t+3], ONE2, s3);
        }
        float l  = __builtin_amdgcn_logf((s0+s1)+(s2+s3));
        float e0 = __builtin_amdgcn_exp2f(-l);
        if (rowAct) {
            ((half1*)Ebuf[0][0])[j + 48] = (half1)e0;
            ((half1*)Ebuf[0][1])[j + 49] = (half1)e0;
        }
        y[0] = rowAct ? __builtin_amdgcn_exp2f(fmaf(INVRHO, l, LOG_A2)) : 0.f;
    }
    __syncthreads();   // B0: guards + init E visible

    // ---- fixed pointers / ownership ----
    const int par  = c0 & 1;
    const int bdw  = (c0 + par) >> 1;           // E window base dword
    const int off1 = v1 ? 32 : 0;               // +64 halfs for c1 (gated)
    half1* const gsA = (half1*)(GS_A + wid * GSS);
    half1* const gsB = (half1*)(GS_B + wid * GSS);
    const int Lr = rowAct ? L : 51;
    const unsigned* const gp = (Lr & 1) ? (GS_B + wid * GSS + ((Lr + 1) >> 1))
                                        : (GS_A + wid * GSS + (Lr >> 1));
    const int lo = (wid < 5) ? (60 * wid + 1) : 301;
    const int nn = (wid < 5) ? 60 : 59;
    const bool own0 = (unsigned)(c0 - lo) < (unsigned)nn;
    const bool own1 = v1 && ((unsigned)(c0 + 64 - lo) < (unsigned)nn);

    // ---- Sinkhorn loop: ONE barrier per iteration ----
    float den = 0.f, ehv = 0.f;
    #pragma unroll
    for (int it = 0; it < NITER; ++it) {
        const unsigned* ep = Ebuf[it & 1][par] + bdw;
        float a0=0,a1=0,a2=0,a3=0, b0=0,b1=0,b2=0,b3=0;
        #pragma unroll
        for (int t = 0; t < 24; t += 4) {
            a0 = fdot2(wc0[t],   ep[t],   a0);
            a1 = fdot2(wc0[t+1], ep[t+1], a1);
            a2 = fdot2(wc0[t+2], ep[t+2], a2);
            a3 = fdot2(wc0[t+3], ep[t+3], a3);
            b0 = fdot2(wc1[t],   ep[t+off1],   b0);
            b1 = fdot2(wc1[t+1], ep[t+1+off1], b1);
            b2 = fdot2(wc1[t+2], ep[t+2+off1], b2);
            b3 = fdot2(wc1[t+3], ep[t+3+off1], b3);
        }
        float l0 = __builtin_amdgcn_logf((a0+a1)+(a2+a3));
        float l1 = __builtin_amdgcn_logf((b0+b1)+(b2+b3));
        float g0 = __builtin_amdgcn_exp2f(-TAU * l0);
        float g1 = __builtin_amdgcn_exp2f(-TAU * l1);
        gsA[L] = (half1)g0;
        gsB[L + 1] = (half1)g0;
        if (v1) { gsA[L + 64] = (half1)g1; gsB[L + 65] = (half1)g1; }
        y[1 + 2*it] = (own0 ? __builtin_amdgcn_exp2f(fmaf(TIR, l0, LOG_B2)) : 0.f)
                    + (own1 ? __builtin_amdgcn_exp2f(fmaf(TIR, l1, LOG_B2)) : 0.f);
        // strip writes must land before this wave reads its strip
        asm volatile("s_waitcnt lgkmcnt(0)" ::: "memory");
        __builtin_amdgcn_sched_barrier(0);

        float r0=0,r1=0,r2=0,r3=0;
        #pragma unroll
        for (int t = 0; t < 24; t += 4) {
            r0 = fdot2(wrow[t],   gp[t],   r0);
            r1 = fdot2(wrow[t+1], gp[t+1], r1);
            r2 = fdot2(wrow[t+2], gp[t+2], r2);
            r3 = fdot2(wrow[t+3], gp[t+3], r3);
        }
        den = (r0+r1)+(r2+r3);
        float lr = __builtin_amdgcn_logf(den);
        ehv = __builtin_amdgcn_exp2f(-TAU * lr);
        if (rowAct) {
            ((half1*)Ebuf[(it+1) & 1][0])[j + 48] = (half1)ehv;
            ((half1*)Ebuf[(it+1) & 1][1])[j + 49] = (half1)ehv;
        }
        y[2 + 2*it] = rowAct ? __builtin_amdgcn_exp2f(fmaf(TIR, lr, LOG_A2)) : 0.f;
        __syncthreads();   // the ONE barrier per iteration
    }

    // ---- reduce the 21 per-lane partials once ----
    #pragma unroll
    for (int p = 0; p < NACC; ++p) {
        float s = dpp_sum64(y[p]);
        if (L == 63) s_red[p * NWAVE + wid] = s;
    }
    __syncthreads();

    // ---- uniform scalar recurrence over the 21 reduction values ----
    float fsh = -LOG_B2, gsh = 0.f;
    {
        float R[NACC];
        #pragma unroll
        for (int p = 0; p < NACC; ++p) {
            const float* rp = s_red + p * NWAVE;
            float s = ((rp[0] + rp[1]) + (rp[2] + rp[3])) + (rp[4] + rp[5]);
            R[p] = __builtin_amdgcn_logf(s);
        }
        float sminF = fsh - RHO * R[0];
        #pragma unroll
        for (int it = 0; it < NITER; ++it) {
            float Cg = TAU * (LOG_B2 - fsh) - KAPPA * sminF;
            float sg = Cg - RHO * R[1 + 2 * it];
            gsh = Cg + XI * sg;
            float sminG = (1.f + XI) * sg;
            float Cf = TAU * (LOG_A2 - gsh) - KAPPA * sminG;
            float sf = Cf - RHO * R[2 + 2 * it];
            fsh = Cf + XI * sf;
            sminF = (1.f + XI) * sf;
        }
    }

    // ---- epilogue: disparity from final wave-local G strip ----
    if (rowAct) {
        float n0 = 0.f, n1 = 0.f;
        #pragma unroll
        for (int t = 0; t < 24; ++t) {
            half2v dc; dc[0] = (half1)(float)(47 - 2 * t); dc[1] = (half1)(float)(46 - 2 * t);
            half2v wd = h2(wrow[t]) * dc;             // v_pk_mul_f16
            float& acc = (t & 1) ? n1 : n0;
            acc = fdot2h(wd, gp[t], acc);
        }
        float E = __builtin_amdgcn_exp2f(fsh + gsh) * ehv;
        float mass = fmaxf(E * den, 1e-8f);
        out[(size_t)bid * WROWS + j] = (E * (n0 + n1)) / mass;
    }
}

extern "C" void kernel_launch(void* const* d_in, const int* in_sizes, int n_in,
                              void* d_out, int out_size, void* d_ws, size_t ws_size,
                              hipStream_t stream) {
    const float* scores = (const float*)d_in[0];
    float* out = (float*)d_out;
    ot_disp_kernel<<<128, NT, 0, stream>>>(scores, out);
}

// Round 15
// 25.296 us; speedup vs baseline: 1.3126x; 1.3126x over previous
//
#include <hip/hip_runtime.h>
#include <math.h>

// Banded unbalanced Sinkhorn OT -> disparity. One (b,h) problem per block,
// 6 waves (384 threads): lane owns ONE col c=tid and ONE row j=tid.
// Hat-recurrence: Ghat = (sum w*Ehat)^-tau, Ehat' = (sum w*Ghat)^-tau; the
// uniform shifts ride in an end-of-kernel scalar recurrence over 21 stored
// reduction values. E/G in LDS fp16 with one shifted replica (A/B) so every
// lane's 48-half window is 24 consecutive dwords. Writes are PAIRED b32:
// DPP wave_shl:1 fetches the right neighbor, even lanes write the A-array
// dword, odd lanes the B-array dword (conflict-free; b16 fixups only at
// wave boundaries). Weights: 48 register dwords/lane straight from global.

typedef _Float16 half1;
typedef _Float16 half2v __attribute__((ext_vector_type(2)));

#define MAXD   48
#define WROWS  312
#define CCOLS  360
#define NITER  10
#define NT     384
#define NWAVE  6
#define NACC   21

__device__ __forceinline__ half2v h2(unsigned v) { return __builtin_bit_cast(half2v, v); }
__device__ __forceinline__ unsigned packf(float x, float y) {
    half2v v; v[0] = (half1)x; v[1] = (half1)y;
    return __builtin_bit_cast(unsigned, v);
}
__device__ __forceinline__ float fdot2(unsigned a, unsigned b, float c) {
    return __builtin_amdgcn_fdot2(h2(a), h2(b), c, false);
}
__device__ __forceinline__ float fdot2h(half2v a, unsigned b, float c) {
    return __builtin_amdgcn_fdot2(a, h2(b), c, false);
}
template <int CTRL>
__device__ __forceinline__ float dpp_add(float x, float acc) {
    int y = __builtin_amdgcn_update_dpp(0, __float_as_int(x), CTRL, 0xf, 0xf, true);
    return acc + __int_as_float(y);
}
__device__ __forceinline__ float dpp_sum64(float x) {   // valid in lane 63
    x = dpp_add<0x111>(x, x);
    x = dpp_add<0x112>(x, x);
    x = dpp_add<0x114>(x, x);
    x = dpp_add<0x118>(x, x);
    x = dpp_add<0x142>(x, x);
    x = dpp_add<0x143>(x, x);
    return x;
}
// lane i <- lane i+1 (0 at lane 63): wave_shl:1
__device__ __forceinline__ float dpp_next(float x) {
    int y = __builtin_amdgcn_update_dpp(0, __float_as_int(x), 0x130, 0xf, 0xf, true);
    return __int_as_float(y);
}

// paired E write: even j -> EA dword (E_j,E_{j+1}); odd j -> EB dword.
__device__ __forceinline__ void write_E(unsigned* EA2, unsigned* EB2,
                                        int j, int L, bool rowAct,
                                        float e, float en) {
    if (!rowAct) return;                       // j in [0,312)
    if (!(j & 1)) {
        EA2[(j + 48) >> 1] = packf(e, en);     // halves (j+48, j+49)
        if (L == 0) ((half1*)EB2)[j + 49] = (half1)e;   // j=0,64,...,256
    } else {
        float e1 = (j == 311) ? 0.f : en;      // half 361 is guard-zero
        if (L != 63) EB2[(j + 49) >> 1] = packf(e, e1);
        else         ((half1*)EB2)[j + 49] = (half1)e;  // j=63,...,255
    }
}
// paired G write: even c -> GA dword (G_c,G_{c+1}); odd c -> GB dword.
__device__ __forceinline__ void write_G(unsigned* GA2, unsigned* GB2,
                                        int c, int L, float g, float gn) {
    if (!(c & 1)) {
        if (c >= 2 && c <= 358) GA2[c >> 1] = packf(g, gn);
        if (L == 0 && c >= 64 && c < 360) ((half1*)GB2)[c + 1] = (half1)g;
    } else if (c <= 357) {
        if (L != 63) GB2[(c + 1) >> 1] = packf(g, gn);
        else         ((half1*)GB2)[c + 1] = (half1)g;   // c=63,...,319
    }                                          // c==359: dword 180 never read
}

__global__ __launch_bounds__(NT, 2)
void ot_disp_kernel(const float* __restrict__ scores, float* __restrict__ out) {
    const int tid = threadIdx.x;
    const int wid = tid >> 6;
    const int L   = tid & 63;
    const int bid = blockIdx.x;                 // 0..127 (= b*64 + h)
    const int b   = bid >> 6, h = bid & 63;

    const float LOG_A2 = -8.2854022f;   // -log2(312)
    const float LOG_B2 = -8.4918531f;   // -log2(360)
    const float TAU = 0.95f, KAPPA = 0.025f, XI = 0.025641026f;
    const float RHO = 19.0f, INVRHO = 0.052631579f, TIR = 0.05f;

    __shared__ unsigned EA2[204], EB2[204], GA2[180], GB2[181];
    __shared__ float s_red[NACC * NWAVE];

    // guard zeros, disjoint from value halves (r12 scheme)
    if (tid < 24) { EA2[tid] = 0u; EA2[180 + tid] = 0u; EB2[tid] = 0u; }
    if (tid < 23) EB2[181 + tid] = 0u;
    if (tid == 30) { ((half1*)EB2)[48] = (half1)0.f; ((half1*)EB2)[361] = (half1)0.f; }

    const bool rowAct = (tid < WROWS);
    const bool colW   = (tid >= 1 && tid < CCOLS);
    const int  c = (tid < CCOLS) ? tid : (CCOLS - 1);
    const int  j = rowAct ? tid : (WROWS - 1);

    const float* src = scores + ((size_t)(b * MAXD) * 64 + h) * WROWS;
    const size_t dstr = (size_t)64 * WROWS;

    // ---- register weight caches (48 dwords), straight from global ----
    unsigned wcol[24];   // pair t = (w_{d=2t}, w_{d=2t+1}),  w_d = e^s[d][c-48+d]
    unsigned wrow[24];   // pair t = (w_{d=47-2t}, w_{d=46-2t}), w_d = e^s[d][j]
    #pragma unroll
    for (int t = 0; t < 24; ++t) {
        int j0 = c - MAXD + 2 * t;
        int j1 = j0 + 1;
        bool v0 = (unsigned)j0 < (unsigned)WROWS;
        bool v1 = (unsigned)j1 < (unsigned)WROWS;
        float x0 = v0 ? __expf(src[(size_t)(2 * t) * dstr + (v0 ? j0 : 0)]) : 0.f;
        float x1 = v1 ? __expf(src[(size_t)(2 * t + 1) * dstr + (v1 ? j1 : 0)]) : 0.f;
        wcol[t] = packf(x0, x1);
    }
    #pragma unroll
    for (int t = 0; t < 24; ++t) {
        float x0 = __expf(src[(size_t)(47 - 2 * t) * dstr + j]);
        float x1 = __expf(src[(size_t)(46 - 2 * t) * dstr + j]);
        wrow[t] = packf(x0, x1);
    }

    // window base pointers (24 consecutive dwords each, parity-resolved)
    const unsigned* const ecp = (c & 1) ? (EB2 + ((c + 1) >> 1)) : (EA2 + (c >> 1));
    const unsigned* const grp = (j & 1) ? (GA2 + ((j + 1) >> 1)) : (GB2 + ((j + 2) >> 1));

    // ---- init: Ehat0 = 1/sum(w_row); y[0] partial in reg ----
    const unsigned ONE2 = 0x3C003C00u;
    float y[NACC];
    {
        float s0=0,s1=0,s2=0,s3=0;
        #pragma unroll
        for (int t = 0; t < 24; t += 4) {
            s0 = fdot2(wrow[t],   ONE2, s0);
            s1 = fdot2(wrow[t+1], ONE2, s1);
            s2 = fdot2(wrow[t+2], ONE2, s2);
            s3 = fdot2(wrow[t+3], ONE2, s3);
        }
        float l  = __builtin_amdgcn_logf((s0+s1)+(s2+s3));
        float e0 = __builtin_amdgcn_exp2f(-l);
        float en = dpp_next(e0);
        write_E(EA2, EB2, j, L, rowAct, e0, en);
        y[0] = rowAct ? __builtin_amdgcn_exp2f(fmaf(INVRHO, l, LOG_A2)) : 0.f;
    }
    __syncthreads();   // B0: guards + init E visible

    // ---- Sinkhorn loop: 2 barriers/iter, lane-local dot2 bands ----
    float den = 0.f, ehv = 0.f;
    #pragma unroll
    for (int it = 0; it < NITER; ++it) {
        // col phase: Ghat_c = (sum_d w * Ehat)^-tau
        float a0=0,a1=0,a2=0,a3=0;
        #pragma unroll
        for (int t = 0; t < 24; t += 4) {
            a0 = fdot2(wcol[t],   ecp[t],   a0);
            a1 = fdot2(wcol[t+1], ecp[t+1], a1);
            a2 = fdot2(wcol[t+2], ecp[t+2], a2);
            a3 = fdot2(wcol[t+3], ecp[t+3], a3);
        }
        float lc = __builtin_amdgcn_logf((a0+a1)+(a2+a3));
        float gh = __builtin_amdgcn_exp2f(-TAU * lc);
        float gn = dpp_next(gh);
        write_G(GA2, GB2, c, L, gh, gn);
        y[1 + 2 * it] = colW ? __builtin_amdgcn_exp2f(fmaf(TIR, lc, LOG_B2)) : 0.f;
        __syncthreads();

        // row phase: Ehat_j = (sum_d w * Ghat)^-tau
        float b0=0,b1=0,b2=0,b3=0;
        #pragma unroll
        for (int t = 0; t < 24; t += 4) {
            b0 = fdot2(wrow[t],   grp[t],   b0);
            b1 = fdot2(wrow[t+1], grp[t+1], b1);
            b2 = fdot2(wrow[t+2], grp[t+2], b2);
            b3 = fdot2(wrow[t+3], grp[t+3], b3);
        }
        den = (b0+b1)+(b2+b3);
        float lr = __builtin_amdgcn_logf(den);
        ehv = __builtin_amdgcn_exp2f(-TAU * lr);
        float en = dpp_next(ehv);
        write_E(EA2, EB2, j, L, rowAct, ehv, en);
        y[2 + 2 * it] = rowAct ? __builtin_amdgcn_exp2f(fmaf(TIR, lr, LOG_A2)) : 0.f;
        __syncthreads();
    }

    // ---- reduce the 21 per-lane partials once (DPP + 6 slots each) ----
    #pragma unroll
    for (int p = 0; p < NACC; ++p) {
        float s = dpp_sum64(y[p]);
        if (L == 63) s_red[p * NWAVE + wid] = s;
    }
    __syncthreads();

    // ---- uniform scalar recurrence from the 21 reduction values ----
    float fsh = -LOG_B2, gsh = 0.f;
    {
        float R[NACC];
        #pragma unroll
        for (int p = 0; p < NACC; ++p) {
            const float* rp = s_red + p * NWAVE;
            float s = ((rp[0] + rp[1]) + (rp[2] + rp[3])) + (rp[4] + rp[5]);
            R[p] = __builtin_amdgcn_logf(s);
        }
        float sminF = fsh - RHO * R[0];
        #pragma unroll
        for (int it = 0; it < NITER; ++it) {
            float Cg = TAU * (LOG_B2 - fsh) - KAPPA * sminF;
            float sg = Cg - RHO * R[1 + 2 * it];
            gsh = Cg + XI * sg;
            float sminG = (1.f + XI) * sg;
            float Cf = TAU * (LOG_A2 - gsh) - KAPPA * sminG;
            float sf = Cf - RHO * R[2 + 2 * it];
            fsh = Cf + XI * sf;
            sminF = (1.f + XI) * sf;
        }
    }

    // ---- epilogue: disparity (G window re-read; den/ehv from last phase) ----
    if (rowAct) {
        float n0 = 0.f, n1 = 0.f;
        #pragma unroll
        for (int t = 0; t < 24; ++t) {
            half2v dc; dc[0] = (half1)(float)(47 - 2 * t); dc[1] = (half1)(float)(46 - 2 * t);
            half2v wd = h2(wrow[t]) * dc;             // v_pk_mul_f16
            float& nn = (t & 1) ? n1 : n0;
            nn = fdot2h(wd, grp[t], nn);
        }
        float E = __builtin_amdgcn_exp2f(fsh + gsh) * ehv;
        float mass = fmaxf(E * den, 1e-8f);
        out[(size_t)bid * WROWS + j] = (E * (n0 + n1)) / mass;
    }
}

extern "C" void kernel_launch(void* const* d_in, const int* in_sizes, int n_in,
                              void* d_out, int out_size, void* d_ws, size_t ws_size,
                              hipStream_t stream) {
    const float* scores = (const float*)d_in[0];
    float* out = (float*)d_out;
    ot_disp_kernel<<<128, NT, 0, stream>>>(scores, out);
}